// Round 9
// baseline (3922.314 us; speedup 1.0000x reference)
//
#include <hip/hip_runtime.h>
#include <math.h>

#define NN 50000      // nodes
#define NE 800000     // edges
#define NP 200000     // link pairs
#define NF 128        // feature dim
#define NNP (NN + 1)          // +1 zero dummy row
#define NBLK 196              // ceil(NN/256)
#define NBK 64                // dst-range buckets
#define DPB 782               // dsts per bucket
#define BKCAP 16384           // bucket capacity
#define EPB 2048              // edges per Phase-A block
#define NSL 2                 // feature slices (128 B f16 rows)
#define SF 64                 // features per slice
#define NCPAD 1000064         // padded cols capacity
#define NVB (((NN + 63) / 64) * 2)   // virtual step blocks = 1564
#define GCHAIN 768            // persistent grid: 3 blocks/CU by launch_bounds

typedef __attribute__((ext_vector_type(8))) short short8;
typedef __attribute__((ext_vector_type(4))) float float4v;
typedef __attribute__((ext_vector_type(2))) _Float16 h2;
typedef __attribute__((ext_vector_type(4))) unsigned short us4;  // native vec
typedef __attribute__((ext_vector_type(4))) unsigned int u32x4;  // native vec

// ---- bf16 helpers (manual, RNE) ----
__device__ __forceinline__ unsigned short f2bf(float f) {
    unsigned u = __float_as_uint(f);
    return (unsigned short)((u + 0x7fffu + ((u >> 16) & 1u)) >> 16);
}
__device__ __forceinline__ unsigned pack2bf(float a, float b) {
    return (unsigned)f2bf(a) | ((unsigned)f2bf(b) << 16);
}

// ---- f16 helpers ----
__device__ __forceinline__ h2 u2h2(unsigned u) {
    union { unsigned u; h2 h; } c; c.u = u; return c.h;
}
__device__ __forceinline__ unsigned h22u(h2 h) {
    union { unsigned u; h2 h; } c; c.h = h; return c.u;
}
__device__ __forceinline__ float h_lo(unsigned u) { return (float)u2h2(u).x; }
__device__ __forceinline__ float h_hi(unsigned u) { return (float)u2h2(u).y; }
__device__ __forceinline__ unsigned pack2h(float a, float b) {
    h2 h; h.x = (_Float16)a; h.y = (_Float16)b; return h22u(h);
}

// ---------------------------------------------------------------------------
// degree count + scan. dinv includes the self-loop (deg = in+1); row_ptr is
// built over REAL in-edges only (self handled analytically in the step),
// padded up to x4 for aligned us4 cols loads.
// ---------------------------------------------------------------------------
__global__ __launch_bounds__(256) void init_cnt_k(int* __restrict__ cnt,
                                                  float4* __restrict__ puv) {
    int i = blockIdx.x * 256 + threadIdx.x;
    if (i < NN) {
        cnt[i] = 1;  // self-loop
        puv[i] = make_float4(0.f, 0.f, 0.f, 0.f);  // mode-2 atomic target
    }
}

__global__ __launch_bounds__(256) void count_k(const int* __restrict__ ei,
                                               int* __restrict__ cnt) {
    int e = blockIdx.x * 256 + threadIdx.x;
    if (e < NE) atomicAdd(&cnt[ei[NE + e]], 1);
}

__global__ __launch_bounds__(256) void scan_reduce_k(const int* __restrict__ cnt,
                                                     int* __restrict__ bsum,
                                                     float* __restrict__ dinv) {
    __shared__ int s[256];
    int t = threadIdx.x;
    int idx = blockIdx.x * 256 + t;
    int v = (idx < NN) ? cnt[idx] : 0;
    if (idx < NN) dinv[idx] = rsqrtf((float)v);
    int vp = (idx < NN) ? ((v + 2) & ~3) : 0;  // (v-1 real edges) padded x4
    s[t] = vp;
    __syncthreads();
    for (int off = 128; off > 0; off >>= 1) {
        if (t < off) s[t] += s[t + off];
        __syncthreads();
    }
    if (t == 0) bsum[blockIdx.x] = s[0];
}

__global__ __launch_bounds__(256) void scan_bsums_k(const int* __restrict__ bsum,
                                                    int* __restrict__ boff) {
    __shared__ int s[256];
    int t = threadIdx.x;
    int v = (t < NBLK) ? bsum[t] : 0;
    s[t] = v;
    __syncthreads();
    for (int off = 1; off < 256; off <<= 1) {
        int add = (t >= off) ? s[t - off] : 0;
        __syncthreads();
        s[t] += add;
        __syncthreads();
    }
    if (t < NBLK) boff[t] = s[t] - v;
}

__global__ __launch_bounds__(256) void scan_down_k(const int* __restrict__ cnt,
                                                   const int* __restrict__ boff,
                                                   int* __restrict__ row_ptr) {
    __shared__ int s[256];
    int t = threadIdx.x;
    int idx = blockIdx.x * 256 + t;
    int v = (idx < NN) ? ((cnt[idx] + 2) & ~3) : 0;
    s[t] = v;
    __syncthreads();
    for (int off = 1; off < 256; off <<= 1) {
        int add = (t >= off) ? s[t - off] : 0;
        __syncthreads();
        s[t] += add;
        __syncthreads();
    }
    int excl = s[t] - v + boff[blockIdx.x] + 4;  // +4: dummy block at cols[0..3]
    if (idx < NN) {
        row_ptr[idx] = excl;
        if (idx == NN - 1) row_ptr[NN] = excl + v;
    }
}

// fill padded cols with the dummy node id NN (pad slots gather the zero row)
__global__ __launch_bounds__(256) void fill_cols_k(unsigned* __restrict__ colsu) {
    int t = blockIdx.x * 256 + threadIdx.x;
    if (t < NCPAD / 2) colsu[t] = (unsigned)NN | ((unsigned)NN << 16);
}

// ---------------------------------------------------------------------------
// Two-phase binned CSR build over REAL edges only. cols u16.
// ---------------------------------------------------------------------------
__global__ __launch_bounds__(256) void bin_k(const int* __restrict__ ei,
                                             int* __restrict__ gtail,
                                             int2* __restrict__ gbk) {
    __shared__ int cntA[NBK], baseA[NBK], gposA[NBK];
    __shared__ int2 stage[EPB];
    int tid = threadIdx.x;
    int ebase = blockIdx.x * EPB;
    int sv[8], dv[8], lp8[8], bk8[8];
    bool val[8];
    if (tid < NBK) cntA[tid] = 0;
    __syncthreads();
#pragma unroll
    for (int k = 0; k < 8; ++k) {
        int e = ebase + k * 256 + tid;
        val[k] = (e < NE);
        if (val[k]) {
            int s = ei[e], d = ei[NE + e];
            sv[k] = s; dv[k] = d;
            bk8[k] = d / DPB;
            lp8[k] = atomicAdd(&cntA[bk8[k]], 1);
        }
    }
    __syncthreads();
    if (tid == 0) {
        int run = 0;
        for (int b = 0; b < NBK; ++b) { baseA[b] = run; run += cntA[b]; }
    }
    __syncthreads();
    if (tid < NBK && cntA[tid] > 0)
        gposA[tid] = atomicAdd(&gtail[tid], cntA[tid]);
    __syncthreads();
#pragma unroll
    for (int k = 0; k < 8; ++k)
        if (val[k]) {
            int2 r; r.x = sv[k]; r.y = dv[k];
            stage[baseA[bk8[k]] + lp8[k]] = r;
        }
    __syncthreads();
    int total = baseA[NBK - 1] + cntA[NBK - 1];
    for (int i = tid; i < total; i += 256) {
        int2 r = stage[i];
        int b = r.y / DPB;
        gbk[(size_t)b * BKCAP + gposA[b] + (i - baseA[b])] = r;
    }
}

__global__ __launch_bounds__(256) void build_k(const int* __restrict__ row_ptr,
                                               const int* __restrict__ gtail,
                                               const int2* __restrict__ gbk,
                                               unsigned short* __restrict__ cols) {
    __shared__ int wcur[DPB];
    int tid = threadIdx.x;
    int b = blockIdx.x;
    int d0 = b * DPB;
    for (int i = tid; i < DPB; i += 256) {
        int d = d0 + i;
        wcur[i] = (d < NN) ? row_ptr[d] : 0;
    }
    __syncthreads();
    int nb = gtail[b];
    const int2* src = gbk + (size_t)b * BKCAP;
    for (int t = tid; t < nb; t += 256) {
        int2 r = src[t];
        int pos = atomicAdd(&wcur[r.y - d0], 1);
        cols[pos] = (unsigned short)r.x;
    }
}

// zero dummy rows (node NN) of both slices of the four f16 state buffers,
// plus the grid-barrier counter.
__global__ __launch_bounds__(256) void zero_k(unsigned short* Ys1, unsigned short* Ys2,
                                              unsigned short* HA, unsigned short* HB,
                                              int* gtail, unsigned* bar) {
    int t = threadIdx.x;
    unsigned short* bufs[4] = {Ys1, Ys2, HA, HB};
    unsigned short* bp = bufs[t >> 6];
    int s = (t >> 5) & 1, u = t & 31;
    ((unsigned*)(bp + ((size_t)s * NNP + NN) * SF))[u] = 0u;
    if (t < NBK) gtail[t] = 0;
    if (t == 0) bar[0] = 0u;
}

// W fp32 -> bf16 row-major
__global__ __launch_bounds__(256) void cast_w_k(const float* __restrict__ W,
                                                unsigned short* __restrict__ Wb) {
    int t = blockIdx.x * 256 + threadIdx.x;
    if (t >= 128 * 128 / 8) return;
    int i = t * 8;
    float4 f0 = *(const float4*)(W + i);
    float4 f1 = *(const float4*)(W + i + 4);
    uint4 q;
    q.x = pack2bf(f0.x, f0.y);
    q.y = pack2bf(f0.z, f0.w);
    q.z = pack2bf(f1.x, f1.y);
    q.w = pack2bf(f1.z, f1.w);
    *(uint4*)(Wb + i) = q;
}

// ---------------------------------------------------------------------------
// MFMA GEMM: Y = X @ W.T + b. Slice-major f16 epilogue [slice][node][64].
// ---------------------------------------------------------------------------
#define GPAD 136
template <bool F32IN>
__global__ __launch_bounds__(256) void gemm_mfma_k(const void* __restrict__ Xv,
                                                   const unsigned short* __restrict__ Wb,
                                                   const float* __restrict__ bias,
                                                   const float* __restrict__ dinv,
                                                   unsigned short* __restrict__ Yu,
                                                   unsigned short* __restrict__ Ys,
                                                   int nrows) {
    __shared__ unsigned short sm[4 * 16 * GPAD];  // 17408 B
    int wave = threadIdx.x >> 6, lane = threadIdx.x & 63;
    int rbase = blockIdx.x * 64 + wave * 16;
    if (rbase >= nrows) return;
    int quad = lane >> 4, mn = lane & 15;
    float4v acc[8];
#pragma unroll
    for (int ft = 0; ft < 8; ++ft) acc[ft] = (float4v){0.f, 0.f, 0.f, 0.f};
#pragma unroll
    for (int kb = 0; kb < 128; kb += 32) {
        short8 a;
        if (F32IN) {
            const float* X = (const float*)Xv;
            float4 f0 = *(const float4*)(X + (size_t)(rbase + mn) * NF + kb + quad * 8);
            float4 f1 = *(const float4*)(X + (size_t)(rbase + mn) * NF + kb + quad * 8 + 4);
            a[0] = (short)f2bf(f0.x); a[1] = (short)f2bf(f0.y);
            a[2] = (short)f2bf(f0.z); a[3] = (short)f2bf(f0.w);
            a[4] = (short)f2bf(f1.x); a[5] = (short)f2bf(f1.y);
            a[6] = (short)f2bf(f1.z); a[7] = (short)f2bf(f1.w);
        } else {
            const unsigned short* X = (const unsigned short*)Xv;
            a = *(const short8*)(X + (size_t)(rbase + mn) * NF + kb + quad * 8);
        }
#pragma unroll
        for (int ft = 0; ft < 8; ++ft) {
            short8 b = *(const short8*)(Wb + (size_t)(ft * 16 + mn) * NF + kb + quad * 8);
            acc[ft] = __builtin_amdgcn_mfma_f32_16x16x32_bf16(a, b, acc[ft], 0, 0, 0);
        }
    }
    unsigned short* smw = sm + wave * 16 * GPAD;
#pragma unroll
    for (int ft = 0; ft < 8; ++ft) {
        float bv = bias[ft * 16 + mn];
#pragma unroll
        for (int r = 0; r < 4; ++r) {
            union { _Float16 h; unsigned short s; } cv;
            cv.h = (_Float16)(acc[ft][r] + bv);
            smw[(quad * 4 + r) * GPAD + ft * 16 + mn] = cv.s;
        }
    }
    __syncthreads();
#pragma unroll
    for (int t = 0; t < 4; ++t) {
        int rl = t * 4 + quad;
        int row = rbase + rl;
        uint4 q = *(const uint4*)(smw + rl * GPAD + mn * 8);
        size_t sb = ((size_t)(mn >> 3) * NNP + row) * SF + (mn & 7) * 8;
        *(uint4*)(Yu + sb) = q;
        float g = dinv[row];
        uint4 qs;
        qs.x = pack2h(g * h_lo(q.x), g * h_hi(q.x));
        qs.y = pack2h(g * h_lo(q.y), g * h_hi(q.y));
        qs.z = pack2h(g * h_lo(q.z), g * h_hi(q.z));
        qs.w = pack2h(g * h_lo(q.w), g * h_hi(q.w));
        *(uint4*)(Ys + sb) = qs;
    }
}

// ---------------------------------------------------------------------------
// APPNP step body (return-free): 128 B rows, self-loop folded, nt-x0,
// 3-deep gather pipeline. vb encodes (slice = vb&1, node block = vb>>1).
// ---------------------------------------------------------------------------
__device__ __forceinline__ void step_body(
    int vb,
    const unsigned short* __restrict__ hs,
    const unsigned short* __restrict__ x0,
    const float* __restrict__ dinv,
    unsigned short* __restrict__ out,
    const int* __restrict__ row_ptr,
    const unsigned short* __restrict__ cols,
    int mode,
    const float* __restrict__ W3,
    float* __restrict__ puv) {
    int s = vb & 1;
    int wave = threadIdx.x >> 6, lane = threadIdx.x & 63;
    int g = lane >> 3, fo = lane & 7;
    int wid = (vb >> 1) * 64 + wave * 8 + g;
    bool valid = wid < NN;
    int nid = valid ? wid : NN;
    const unsigned short* hsS = hs + (size_t)s * NNP * SF;
    int fb8 = fo * 8;
    int beg = 0, dp = 0;
    if (valid) { beg = row_ptr[wid]; dp = row_ptr[wid + 1] - beg; }
    int dpm = dp;
    dpm = max(dpm, __shfl_xor(dpm, 8, 64));
    dpm = max(dpm, __shfl_xor(dpm, 16, 64));
    dpm = max(dpm, __shfl_xor(dpm, 32, 64));
    float gsc = valid ? dinv[wid] : 0.f;
    u32x4 xq = __builtin_nontemporal_load(
        (const u32x4*)(x0 + ((size_t)s * NNP + nid) * SF + fb8));
    uint4 own = *(const uint4*)(hsS + (size_t)nid * SF + fb8);
    h2 a01; a01.x = (_Float16)0.f; a01.y = (_Float16)0.f;
    h2 a23 = a01, a45 = a01, a67 = a01;
    if (dpm > 0) {
        auto colsat = [&](int j4) -> us4 {
            int o = (j4 < dp) ? beg + j4 : 0;  // pads -> dummy block
            return __builtin_nontemporal_load((const us4*)(cols + o));
        };
        auto gat = [&](unsigned short c) -> uint4 {
            return *(const uint4*)(hsS + (size_t)c * SF + fb8);
        };
        us4 cq0 = colsat(0);
        us4 cq1 = colsat(4);
        us4 cq2 = colsat(8);
        us4 cq3 = colsat(12);
        uint4 A0 = gat(cq0.x), A1 = gat(cq0.y), A2 = gat(cq0.z), A3 = gat(cq0.w);
        uint4 B0 = gat(cq1.x), B1 = gat(cq1.y), B2 = gat(cq1.z), B3 = gat(cq1.w);
        uint4 C0 = gat(cq2.x), C1 = gat(cq2.y), C2 = gat(cq2.z), C3 = gat(cq2.w);
        for (int j = 0; j < dpm; j += 4) {
            us4 cq4 = colsat(j + 16);
            uint4 D0 = gat(cq3.x), D1 = gat(cq3.y), D2 = gat(cq3.z), D3 = gat(cq3.w);
            a01 += (u2h2(A0.x) + u2h2(A1.x)) + (u2h2(A2.x) + u2h2(A3.x));
            a23 += (u2h2(A0.y) + u2h2(A1.y)) + (u2h2(A2.y) + u2h2(A3.y));
            a45 += (u2h2(A0.z) + u2h2(A1.z)) + (u2h2(A2.z) + u2h2(A3.z));
            a67 += (u2h2(A0.w) + u2h2(A1.w)) + (u2h2(A2.w) + u2h2(A3.w));
            A0 = B0; A1 = B1; A2 = B2; A3 = B3;
            B0 = C0; B1 = C1; B2 = C2; B3 = C3;
            C0 = D0; C1 = D1; C2 = D2; C3 = D3;
            cq3 = cq4;
        }
    }
    a01 += u2h2(own.x);
    a23 += u2h2(own.y);
    a45 += u2h2(own.z);
    a67 += u2h2(own.w);
    float s9 = 0.9f * gsc;
    float h0 = s9 * (float)a01.x + 0.1f * h_lo(xq.x);
    float h1 = s9 * (float)a01.y + 0.1f * h_hi(xq.x);
    float h2v = s9 * (float)a23.x + 0.1f * h_lo(xq.y);
    float h3 = s9 * (float)a23.y + 0.1f * h_hi(xq.y);
    float h4 = s9 * (float)a45.x + 0.1f * h_lo(xq.z);
    float h5 = s9 * (float)a45.y + 0.1f * h_hi(xq.z);
    float h6 = s9 * (float)a67.x + 0.1f * h_lo(xq.w);
    float h7 = s9 * (float)a67.y + 0.1f * h_hi(xq.w);
    if (mode == 0) {
        if (valid) {
            uint4 oq;
            oq.x = pack2h(gsc * h0, gsc * h1);
            oq.y = pack2h(gsc * h2v, gsc * h3);
            oq.z = pack2h(gsc * h4, gsc * h5);
            oq.w = pack2h(gsc * h6, gsc * h7);
            *(uint4*)(out + ((size_t)s * NNP + wid) * SF + fb8) = oq;
        }
    } else {
        h0 = fmaxf(h0, 0.f); h1 = fmaxf(h1, 0.f);
        h2v = fmaxf(h2v, 0.f); h3 = fmaxf(h3, 0.f);
        h4 = fmaxf(h4, 0.f); h5 = fmaxf(h5, 0.f);
        h6 = fmaxf(h6, 0.f); h7 = fmaxf(h7, 0.f);
        if (mode == 1) {
            if (valid) {
                u32x4 oq;
                oq.x = pack2bf(h0, h1);
                oq.y = pack2bf(h2v, h3);
                oq.z = pack2bf(h4, h5);
                oq.w = pack2bf(h6, h7);
                __builtin_nontemporal_store(
                    oq, (u32x4*)(out + (size_t)wid * NF + s * SF + fb8));
            }
        } else {
            int fb = s * SF + fb8;
            float4 wu0a = *(const float4*)(W3 + fb);
            float4 wu0b = *(const float4*)(W3 + fb + 4);
            float4 wv0a = *(const float4*)(W3 + 128 + fb);
            float4 wv0b = *(const float4*)(W3 + 128 + fb + 4);
            float4 wu1a = *(const float4*)(W3 + 256 + fb);
            float4 wu1b = *(const float4*)(W3 + 256 + fb + 4);
            float4 wv1a = *(const float4*)(W3 + 384 + fb);
            float4 wv1b = *(const float4*)(W3 + 384 + fb + 4);
            float du0 = h0 * wu0a.x + h1 * wu0a.y + h2v * wu0a.z + h3 * wu0a.w
                      + h4 * wu0b.x + h5 * wu0b.y + h6 * wu0b.z + h7 * wu0b.w;
            float du1 = h0 * wu1a.x + h1 * wu1a.y + h2v * wu1a.z + h3 * wu1a.w
                      + h4 * wu1b.x + h5 * wu1b.y + h6 * wu1b.z + h7 * wu1b.w;
            float dv0 = h0 * wv0a.x + h1 * wv0a.y + h2v * wv0a.z + h3 * wv0a.w
                      + h4 * wv0b.x + h5 * wv0b.y + h6 * wv0b.z + h7 * wv0b.w;
            float dv1 = h0 * wv1a.x + h1 * wv1a.y + h2v * wv1a.z + h3 * wv1a.w
                      + h4 * wv1b.x + h5 * wv1b.y + h6 * wv1b.z + h7 * wv1b.w;
            du0 += __shfl_xor(du0, 1, 64); du0 += __shfl_xor(du0, 2, 64);
            du0 += __shfl_xor(du0, 4, 64);
            du1 += __shfl_xor(du1, 1, 64); du1 += __shfl_xor(du1, 2, 64);
            du1 += __shfl_xor(du1, 4, 64);
            dv0 += __shfl_xor(dv0, 1, 64); dv0 += __shfl_xor(dv0, 2, 64);
            dv0 += __shfl_xor(dv0, 4, 64);
            dv1 += __shfl_xor(dv1, 1, 64); dv1 += __shfl_xor(dv1, 2, 64);
            dv1 += __shfl_xor(dv1, 4, 64);
            if (valid && fo < 4) {
                float v = (fo == 0) ? du0 : (fo == 1) ? du1
                          : (fo == 2) ? dv0 : dv1;
                atomicAdd(&puv[(size_t)wid * 4 + fo], v);
            }
        }
    }
}

// ---------------------------------------------------------------------------
// Monotone-counter grid barrier (device scope, per G16). All GCHAIN blocks
// are co-resident (capacity guaranteed by __launch_bounds__(512,6): VGPR
// capped for >=6 waves/SIMD = 3 blocks/CU; 256 CU x 3 = 768 = GCHAIN).
// Counter never resets mid-launch; each launch adds exactly 9*GCHAIN.
// ---------------------------------------------------------------------------
__device__ __forceinline__ void grid_bar(unsigned* bar, unsigned nb) {
    __syncthreads();
    if (threadIdx.x == 0) {
        __threadfence();  // release: publish this block's writes (device scope)
        unsigned old = __hip_atomic_fetch_add(bar, 1u, __ATOMIC_ACQ_REL,
                                              __HIP_MEMORY_SCOPE_AGENT);
        unsigned target = (old / nb + 1u) * nb;
        while (__hip_atomic_load(bar, __ATOMIC_ACQUIRE,
                                 __HIP_MEMORY_SCOPE_AGENT) < target) {
            __builtin_amdgcn_s_sleep(2);
        }
        __threadfence();  // acquire: discard stale cached lines
    }
    __syncthreads();
}

// ---------------------------------------------------------------------------
// Fused 10-step APPNP chain: one PLAIN launch per layer (graph-capture safe).
// Persistent grid-strides over NVB virtual blocks; grid barrier between steps.
// ---------------------------------------------------------------------------
__global__ __launch_bounds__(512, 6) void appnp_chain_k(
    const unsigned short* __restrict__ hs0,
    const unsigned short* __restrict__ x0,
    const float* __restrict__ dinv,
    unsigned short* __restrict__ bufA,
    unsigned short* __restrict__ bufB,
    unsigned short* __restrict__ outF,
    const int* __restrict__ row_ptr,
    const unsigned short* __restrict__ cols,
    int finalMode,
    const float* __restrict__ W3,
    float* __restrict__ puv,
    unsigned* __restrict__ bar) {
    for (int k = 0; k < 10; ++k) {
        const unsigned short* src = (k == 0) ? hs0 : ((k & 1) ? bufA : bufB);
        unsigned short* dst = (k == 9) ? outF : ((k & 1) ? bufB : bufA);
        int mode = (k == 9) ? finalMode : 0;
        for (int vb = blockIdx.x; vb < NVB; vb += GCHAIN)
            step_body(vb, src, x0, dinv, dst, row_ptr, cols, mode, W3, puv);
        if (k < 9) grid_bar(bar, (unsigned)GCHAIN);
    }
}

// ---------------------------------------------------------------------------
// Pair head from precomputed projections: one thread per pair.
// ---------------------------------------------------------------------------
__global__ __launch_bounds__(256) void pair2_k(const float4* __restrict__ puv,
                                               const int2* __restrict__ index,
                                               const float* __restrict__ b3,
                                               float* __restrict__ outp) {
    int p = blockIdx.x * 256 + threadIdx.x;
    if (p >= NP) return;
    int2 uv = index[p];
    float4 a = puv[uv.x];
    float4 b = puv[uv.y];
    float s0 = a.x + b.z + b3[0];
    float s1 = a.y + b.w + b3[1];
    float m = fmaxf(s0, s1);
    float lse = m + logf(expf(s0 - m) + expf(s1 - m));
    *(float2*)(outp + (size_t)p * 2) = make_float2(s0 - lse, s1 - lse);
}

// ---------------------------------------------------------------------------
// Launch
// ---------------------------------------------------------------------------
extern "C" void kernel_launch(void* const* d_in, const int* in_sizes, int n_in,
                              void* d_out, int out_size, void* d_ws, size_t ws_size,
                              hipStream_t stream) {
    const float* x  = (const float*)d_in[0];
    const int* ei   = (const int*)d_in[1];
    const int* idx  = (const int*)d_in[2];
    const float* W1 = (const float*)d_in[3];
    const float* b1 = (const float*)d_in[4];
    const float* W2 = (const float*)d_in[5];
    const float* b2 = (const float*)d_in[6];
    const float* W3 = (const float*)d_in[7];
    const float* b3 = (const float*)d_in[8];
    float* out = (float*)d_out;

    char* ws = (char*)d_ws;
    size_t off = 0;
    auto alloc = [&](size_t bytes) -> void* {
        void* p = ws + off;
        off = (off + bytes + 255) & ~(size_t)255;
        return p;
    };
    const size_t HROWS = (size_t)NSL * NNP * SF;  // slice-major f16 state elems
    int*   cnt     = (int*)  alloc(NN * sizeof(int));
    float* dinv    = (float*)alloc(NN * sizeof(float));
    int*   row_ptr = (int*)  alloc((NN + 1) * sizeof(int));
    int*   bsum    = (int*)  alloc(NBLK * sizeof(int));
    int*   boff    = (int*)  alloc(NBLK * sizeof(int));
    int*   gtail   = (int*)  alloc(NBK * sizeof(int));
    unsigned* bar  = (unsigned*)alloc(256);
    int2*  gbk     = (int2*) alloc((size_t)NBK * BKCAP * sizeof(int2));  // 8 MB
    unsigned short* cols = (unsigned short*)alloc((size_t)NCPAD * 2);
    float4* puv    = (float4*)alloc((size_t)NN * sizeof(float4));
    unsigned short* Wb1 = (unsigned short*)alloc(128 * 128 * 2);
    unsigned short* Wb2 = (unsigned short*)alloc(128 * 128 * 2);
    unsigned short* Yu1 = (unsigned short*)alloc(HROWS * 2);
    unsigned short* Ys1 = (unsigned short*)alloc(HROWS * 2);
    unsigned short* Yu2 = (unsigned short*)alloc(HROWS * 2);
    unsigned short* Ys2 = (unsigned short*)alloc(HROWS * 2);
    unsigned short* HA  = (unsigned short*)alloc(HROWS * 2);
    unsigned short* HB  = (unsigned short*)alloc(HROWS * 2);
    unsigned short* Hrelu = (unsigned short*)alloc((size_t)NN * NF * 2);

    const int gN    = (NN + 255) / 256;
    const int gE    = (NE + 255) / 256;
    const int gBin  = (NE + EPB - 1) / EPB;
    const int gGemm = (NN + 63) / 64;             // wave per 16 rows
    const int gFill = (NCPAD / 2 + 255) / 256;
    const int gPair = (NP + 255) / 256;           // thread per pair

    // ---- weights + gcn_norm + padded binned CSR ----
    cast_w_k<<<8, 256, 0, stream>>>(W1, Wb1);
    cast_w_k<<<8, 256, 0, stream>>>(W2, Wb2);
    zero_k<<<1, 256, 0, stream>>>(Ys1, Ys2, HA, HB, gtail, bar);
    init_cnt_k<<<gN, 256, 0, stream>>>(cnt, puv);
    count_k<<<gE, 256, 0, stream>>>(ei, cnt);
    scan_reduce_k<<<NBLK, 256, 0, stream>>>(cnt, bsum, dinv);
    scan_bsums_k<<<1, 256, 0, stream>>>(bsum, boff);
    scan_down_k<<<NBLK, 256, 0, stream>>>(cnt, boff, row_ptr);
    fill_cols_k<<<gFill, 256, 0, stream>>>((unsigned*)cols);
    bin_k<<<gBin, 256, 0, stream>>>(ei, gtail, gbk);
    build_k<<<NBK, 256, 0, stream>>>(row_ptr, gtail, gbk, cols);

    float* puvf = (float*)puv;
    // ---- layer 1 ----
    gemm_mfma_k<true><<<gGemm, 256, 0, stream>>>(x, Wb1, b1, dinv, Yu1, Ys1, NN);
    appnp_chain_k<<<GCHAIN, 512, 0, stream>>>(Ys1, Yu1, dinv, HA, HB, Hrelu,
                                              row_ptr, cols, 1, W3, puvf, bar);
    // ---- layer 2 ----
    gemm_mfma_k<false><<<gGemm, 256, 0, stream>>>(Hrelu, Wb2, b2, dinv, Yu2, Ys2, NN);
    appnp_chain_k<<<GCHAIN, 512, 0, stream>>>(Ys2, Yu2, dinv, HA, HB, HA,
                                              row_ptr, cols, 2, W3, puvf, bar);
    // ---- pair head ----
    pair2_k<<<gPair, 256, 0, stream>>>(puv, (const int2*)idx, b3, out);
}

// Round 10
// 750.790 us; speedup vs baseline: 5.2242x; 5.2242x over previous
//
#include <hip/hip_runtime.h>
#include <math.h>

#define NN 50000      // nodes
#define NE 800000     // edges
#define NP 200000     // link pairs
#define NF 128        // feature dim
#define NNP (NN + 1)          // +1 zero dummy row
#define NBLK 196              // ceil(NN/256)
#define NBK 64                // dst-range buckets
#define DPB 782               // dsts per bucket
#define BKCAP 16384           // bucket capacity
#define EPB 2048              // edges per Phase-A block
#define NSL 2                 // feature slices (128 B f16 rows)
#define SF 64                 // features per slice
#define NCPAD 1000064         // padded cols capacity

typedef __attribute__((ext_vector_type(8))) short short8;
typedef __attribute__((ext_vector_type(4))) float float4v;
typedef __attribute__((ext_vector_type(2))) _Float16 h2;
typedef __attribute__((ext_vector_type(4))) unsigned short us4;  // native vec
typedef __attribute__((ext_vector_type(4))) unsigned int u32x4;  // native vec

// ---- bf16 helpers (manual, RNE) ----
__device__ __forceinline__ unsigned short f2bf(float f) {
    unsigned u = __float_as_uint(f);
    return (unsigned short)((u + 0x7fffu + ((u >> 16) & 1u)) >> 16);
}
__device__ __forceinline__ unsigned pack2bf(float a, float b) {
    return (unsigned)f2bf(a) | ((unsigned)f2bf(b) << 16);
}

// ---- f16 helpers ----
__device__ __forceinline__ h2 u2h2(unsigned u) {
    union { unsigned u; h2 h; } c; c.u = u; return c.h;
}
__device__ __forceinline__ unsigned h22u(h2 h) {
    union { unsigned u; h2 h; } c; c.h = h; return c.u;
}
__device__ __forceinline__ float h_lo(unsigned u) { return (float)u2h2(u).x; }
__device__ __forceinline__ float h_hi(unsigned u) { return (float)u2h2(u).y; }
__device__ __forceinline__ unsigned pack2h(float a, float b) {
    h2 h; h.x = (_Float16)a; h.y = (_Float16)b; return h22u(h);
}

// ---------------------------------------------------------------------------
// degree count + scan. dinv includes the self-loop (deg = in+1); row_ptr is
// built over REAL in-edges only (self handled analytically in the step),
// padded up to x4 for aligned us4 cols loads.
// ---------------------------------------------------------------------------
__global__ __launch_bounds__(256) void init_cnt_k(int* __restrict__ cnt,
                                                  float4* __restrict__ puv) {
    int i = blockIdx.x * 256 + threadIdx.x;
    if (i < NN) {
        cnt[i] = 1;  // self-loop
        puv[i] = make_float4(0.f, 0.f, 0.f, 0.f);  // mode-2 atomic target
    }
}

__global__ __launch_bounds__(256) void count_k(const int* __restrict__ ei,
                                               int* __restrict__ cnt) {
    int e = blockIdx.x * 256 + threadIdx.x;
    if (e < NE) atomicAdd(&cnt[ei[NE + e]], 1);
}

__global__ __launch_bounds__(256) void scan_reduce_k(const int* __restrict__ cnt,
                                                     int* __restrict__ bsum,
                                                     float* __restrict__ dinv) {
    __shared__ int s[256];
    int t = threadIdx.x;
    int idx = blockIdx.x * 256 + t;
    int v = (idx < NN) ? cnt[idx] : 0;
    if (idx < NN) dinv[idx] = rsqrtf((float)v);
    int vp = (idx < NN) ? ((v + 2) & ~3) : 0;  // (v-1 real edges) padded x4
    s[t] = vp;
    __syncthreads();
    for (int off = 128; off > 0; off >>= 1) {
        if (t < off) s[t] += s[t + off];
        __syncthreads();
    }
    if (t == 0) bsum[blockIdx.x] = s[0];
}

__global__ __launch_bounds__(256) void scan_bsums_k(const int* __restrict__ bsum,
                                                    int* __restrict__ boff) {
    __shared__ int s[256];
    int t = threadIdx.x;
    int v = (t < NBLK) ? bsum[t] : 0;
    s[t] = v;
    __syncthreads();
    for (int off = 1; off < 256; off <<= 1) {
        int add = (t >= off) ? s[t - off] : 0;
        __syncthreads();
        s[t] += add;
        __syncthreads();
    }
    if (t < NBLK) boff[t] = s[t] - v;
}

__global__ __launch_bounds__(256) void scan_down_k(const int* __restrict__ cnt,
                                                   const int* __restrict__ boff,
                                                   int* __restrict__ row_ptr) {
    __shared__ int s[256];
    int t = threadIdx.x;
    int idx = blockIdx.x * 256 + t;
    int v = (idx < NN) ? ((cnt[idx] + 2) & ~3) : 0;
    s[t] = v;
    __syncthreads();
    for (int off = 1; off < 256; off <<= 1) {
        int add = (t >= off) ? s[t - off] : 0;
        __syncthreads();
        s[t] += add;
        __syncthreads();
    }
    int excl = s[t] - v + boff[blockIdx.x] + 4;  // +4: dummy block at cols[0..3]
    if (idx < NN) {
        row_ptr[idx] = excl;
        if (idx == NN - 1) row_ptr[NN] = excl + v;
    }
}

// fill padded cols with the dummy node id NN (pad slots gather the zero row)
__global__ __launch_bounds__(256) void fill_cols_k(unsigned* __restrict__ colsu) {
    int t = blockIdx.x * 256 + threadIdx.x;
    if (t < NCPAD / 2) colsu[t] = (unsigned)NN | ((unsigned)NN << 16);
}

// ---------------------------------------------------------------------------
// Two-phase binned CSR build over REAL edges only. cols u16.
// ---------------------------------------------------------------------------
__global__ __launch_bounds__(256) void bin_k(const int* __restrict__ ei,
                                             int* __restrict__ gtail,
                                             int2* __restrict__ gbk) {
    __shared__ int cntA[NBK], baseA[NBK], gposA[NBK];
    __shared__ int2 stage[EPB];
    int tid = threadIdx.x;
    int ebase = blockIdx.x * EPB;
    int sv[8], dv[8], lp8[8], bk8[8];
    bool val[8];
    if (tid < NBK) cntA[tid] = 0;
    __syncthreads();
#pragma unroll
    for (int k = 0; k < 8; ++k) {
        int e = ebase + k * 256 + tid;
        val[k] = (e < NE);
        if (val[k]) {
            int s = ei[e], d = ei[NE + e];
            sv[k] = s; dv[k] = d;
            bk8[k] = d / DPB;
            lp8[k] = atomicAdd(&cntA[bk8[k]], 1);
        }
    }
    __syncthreads();
    if (tid == 0) {
        int run = 0;
        for (int b = 0; b < NBK; ++b) { baseA[b] = run; run += cntA[b]; }
    }
    __syncthreads();
    if (tid < NBK && cntA[tid] > 0)
        gposA[tid] = atomicAdd(&gtail[tid], cntA[tid]);
    __syncthreads();
#pragma unroll
    for (int k = 0; k < 8; ++k)
        if (val[k]) {
            int2 r; r.x = sv[k]; r.y = dv[k];
            stage[baseA[bk8[k]] + lp8[k]] = r;
        }
    __syncthreads();
    int total = baseA[NBK - 1] + cntA[NBK - 1];
    for (int i = tid; i < total; i += 256) {
        int2 r = stage[i];
        int b = r.y / DPB;
        gbk[(size_t)b * BKCAP + gposA[b] + (i - baseA[b])] = r;
    }
}

__global__ __launch_bounds__(256) void build_k(const int* __restrict__ row_ptr,
                                               const int* __restrict__ gtail,
                                               const int2* __restrict__ gbk,
                                               unsigned short* __restrict__ cols) {
    __shared__ int wcur[DPB];
    int tid = threadIdx.x;
    int b = blockIdx.x;
    int d0 = b * DPB;
    for (int i = tid; i < DPB; i += 256) {
        int d = d0 + i;
        wcur[i] = (d < NN) ? row_ptr[d] : 0;
    }
    __syncthreads();
    int nb = gtail[b];
    const int2* src = gbk + (size_t)b * BKCAP;
    for (int t = tid; t < nb; t += 256) {
        int2 r = src[t];
        int pos = atomicAdd(&wcur[r.y - d0], 1);
        cols[pos] = (unsigned short)r.x;
    }
}

// zero dummy rows (node NN) of both slices of the four f16 state buffers.
__global__ __launch_bounds__(256) void zero_k(unsigned short* Ys1, unsigned short* Ys2,
                                              unsigned short* HA, unsigned short* HB,
                                              int* gtail) {
    int t = threadIdx.x;
    unsigned short* bufs[4] = {Ys1, Ys2, HA, HB};
    unsigned short* bp = bufs[t >> 6];
    int s = (t >> 5) & 1, u = t & 31;
    ((unsigned*)(bp + ((size_t)s * NNP + NN) * SF))[u] = 0u;
    if (t < NBK) gtail[t] = 0;
}

// W fp32 -> bf16 row-major
__global__ __launch_bounds__(256) void cast_w_k(const float* __restrict__ W,
                                                unsigned short* __restrict__ Wb) {
    int t = blockIdx.x * 256 + threadIdx.x;
    if (t >= 128 * 128 / 8) return;
    int i = t * 8;
    float4 f0 = *(const float4*)(W + i);
    float4 f1 = *(const float4*)(W + i + 4);
    uint4 q;
    q.x = pack2bf(f0.x, f0.y);
    q.y = pack2bf(f0.z, f0.w);
    q.z = pack2bf(f1.x, f1.y);
    q.w = pack2bf(f1.z, f1.w);
    *(uint4*)(Wb + i) = q;
}

// ---------------------------------------------------------------------------
// MFMA GEMM: Y = X @ W.T + b. Slice-major f16 epilogue [slice][node][64].
// ---------------------------------------------------------------------------
#define GPAD 136
template <bool F32IN>
__global__ __launch_bounds__(256) void gemm_mfma_k(const void* __restrict__ Xv,
                                                   const unsigned short* __restrict__ Wb,
                                                   const float* __restrict__ bias,
                                                   const float* __restrict__ dinv,
                                                   unsigned short* __restrict__ Yu,
                                                   unsigned short* __restrict__ Ys,
                                                   int nrows) {
    __shared__ unsigned short sm[4 * 16 * GPAD];  // 17408 B
    int wave = threadIdx.x >> 6, lane = threadIdx.x & 63;
    int rbase = blockIdx.x * 64 + wave * 16;
    if (rbase >= nrows) return;
    int quad = lane >> 4, mn = lane & 15;
    float4v acc[8];
#pragma unroll
    for (int ft = 0; ft < 8; ++ft) acc[ft] = (float4v){0.f, 0.f, 0.f, 0.f};
#pragma unroll
    for (int kb = 0; kb < 128; kb += 32) {
        short8 a;
        if (F32IN) {
            const float* X = (const float*)Xv;
            float4 f0 = *(const float4*)(X + (size_t)(rbase + mn) * NF + kb + quad * 8);
            float4 f1 = *(const float4*)(X + (size_t)(rbase + mn) * NF + kb + quad * 8 + 4);
            a[0] = (short)f2bf(f0.x); a[1] = (short)f2bf(f0.y);
            a[2] = (short)f2bf(f0.z); a[3] = (short)f2bf(f0.w);
            a[4] = (short)f2bf(f1.x); a[5] = (short)f2bf(f1.y);
            a[6] = (short)f2bf(f1.z); a[7] = (short)f2bf(f1.w);
        } else {
            const unsigned short* X = (const unsigned short*)Xv;
            a = *(const short8*)(X + (size_t)(rbase + mn) * NF + kb + quad * 8);
        }
#pragma unroll
        for (int ft = 0; ft < 8; ++ft) {
            short8 b = *(const short8*)(Wb + (size_t)(ft * 16 + mn) * NF + kb + quad * 8);
            acc[ft] = __builtin_amdgcn_mfma_f32_16x16x32_bf16(a, b, acc[ft], 0, 0, 0);
        }
    }
    unsigned short* smw = sm + wave * 16 * GPAD;
#pragma unroll
    for (int ft = 0; ft < 8; ++ft) {
        float bv = bias[ft * 16 + mn];
#pragma unroll
        for (int r = 0; r < 4; ++r) {
            union { _Float16 h; unsigned short s; } cv;
            cv.h = (_Float16)(acc[ft][r] + bv);
            smw[(quad * 4 + r) * GPAD + ft * 16 + mn] = cv.s;
        }
    }
    __syncthreads();
#pragma unroll
    for (int t = 0; t < 4; ++t) {
        int rl = t * 4 + quad;
        int row = rbase + rl;
        uint4 q = *(const uint4*)(smw + rl * GPAD + mn * 8);
        size_t sb = ((size_t)(mn >> 3) * NNP + row) * SF + (mn & 7) * 8;
        *(uint4*)(Yu + sb) = q;
        float g = dinv[row];
        uint4 qs;
        qs.x = pack2h(g * h_lo(q.x), g * h_hi(q.x));
        qs.y = pack2h(g * h_lo(q.y), g * h_hi(q.y));
        qs.z = pack2h(g * h_lo(q.z), g * h_hi(q.z));
        qs.w = pack2h(g * h_lo(q.w), g * h_hi(q.w));
        *(uint4*)(Ys + sb) = qs;
    }
}

// ---------------------------------------------------------------------------
// APPNP step, 128 B rows, self-loop folded, nt-x0, 3-deep gather pipeline.
//   slice s = b&1; wave = 8 groups x 8 lanes; group g owns dst wid; lane fo
//   owns feats fo*8..fo*8+7 (16 B uint4 gather). CSR has real edges only;
//   self contribution = hs[wid] added via a coalesced sequential read.
//   x0 loads + mode-1 stores nontemporal (keep L2 for hs).
//   mode 0: out = dinv*h_new (slice-major f16)
//   mode 1: out = relu(h_new) (node-major bf16, GEMM2 input)
//   mode 2: relu + per-slice partial W3 projection, atomicAdd into puv
// Measured floor: ~31 us/step == ~5.6 cy per 64B sector-touch per CU
// (invariant to slicing r2/r4/r5, FETCH volume r6, fusion r8).
// ---------------------------------------------------------------------------
__global__ __launch_bounds__(512) void appnp_slice_k(
    const unsigned short* __restrict__ hs,
    const unsigned short* __restrict__ x0,
    const float* __restrict__ dinv,
    unsigned short* __restrict__ out,
    const int* __restrict__ row_ptr,
    const unsigned short* __restrict__ cols,
    int mode,
    const float* __restrict__ W3,
    float* __restrict__ puv) {
    int b = blockIdx.x;
    int s = b & 1;
    int wave = threadIdx.x >> 6, lane = threadIdx.x & 63;
    int g = lane >> 3, fo = lane & 7;
    int wid = (b >> 1) * 64 + wave * 8 + g;
    bool valid = wid < NN;
    int nid = valid ? wid : NN;
    const unsigned short* hsS = hs + (size_t)s * NNP * SF;
    int fb8 = fo * 8;
    int beg = 0, dp = 0;
    if (valid) { beg = row_ptr[wid]; dp = row_ptr[wid + 1] - beg; }
    // wave-max padded degree
    int dpm = dp;
    dpm = max(dpm, __shfl_xor(dpm, 8, 64));
    dpm = max(dpm, __shfl_xor(dpm, 16, 64));
    dpm = max(dpm, __shfl_xor(dpm, 32, 64));
    // prefetch epilogue + self-row operands (sequential, coalesced)
    float gsc = valid ? dinv[wid] : 0.f;
    u32x4 xq = __builtin_nontemporal_load(
        (const u32x4*)(x0 + ((size_t)s * NNP + nid) * SF + fb8));
    uint4 own = *(const uint4*)(hsS + (size_t)nid * SF + fb8);
    h2 a01; a01.x = (_Float16)0.f; a01.y = (_Float16)0.f;
    h2 a23 = a01, a45 = a01, a67 = a01;
    if (dpm > 0) {
        auto colsat = [&](int j4) -> us4 {
            int o = (j4 < dp) ? beg + j4 : 0;  // pads -> dummy block
            return __builtin_nontemporal_load((const us4*)(cols + o));
        };
        auto gat = [&](unsigned short c) -> uint4 {
            return *(const uint4*)(hsS + (size_t)c * SF + fb8);
        };
        us4 cq0 = colsat(0);
        us4 cq1 = colsat(4);
        us4 cq2 = colsat(8);
        us4 cq3 = colsat(12);
        uint4 A0 = gat(cq0.x), A1 = gat(cq0.y), A2 = gat(cq0.z), A3 = gat(cq0.w);
        uint4 B0 = gat(cq1.x), B1 = gat(cq1.y), B2 = gat(cq1.z), B3 = gat(cq1.w);
        uint4 C0 = gat(cq2.x), C1 = gat(cq2.y), C2 = gat(cq2.z), C3 = gat(cq2.w);
        for (int j = 0; j < dpm; j += 4) {
            us4 cq4 = colsat(j + 16);
            uint4 D0 = gat(cq3.x), D1 = gat(cq3.y), D2 = gat(cq3.z), D3 = gat(cq3.w);
            a01 += (u2h2(A0.x) + u2h2(A1.x)) + (u2h2(A2.x) + u2h2(A3.x));
            a23 += (u2h2(A0.y) + u2h2(A1.y)) + (u2h2(A2.y) + u2h2(A3.y));
            a45 += (u2h2(A0.z) + u2h2(A1.z)) + (u2h2(A2.z) + u2h2(A3.z));
            a67 += (u2h2(A0.w) + u2h2(A1.w)) + (u2h2(A2.w) + u2h2(A3.w));
            A0 = B0; A1 = B1; A2 = B2; A3 = B3;
            B0 = C0; B1 = C1; B2 = C2; B3 = C3;
            C0 = D0; C1 = D1; C2 = D2; C3 = D3;
            cq3 = cq4;
        }
    }
    // self-loop contribution (norm_self * h_own = dinv * hs_own folded in agg)
    a01 += u2h2(own.x);
    a23 += u2h2(own.y);
    a45 += u2h2(own.z);
    a67 += u2h2(own.w);
    float s9 = 0.9f * gsc;
    float h0 = s9 * (float)a01.x + 0.1f * h_lo(xq.x);
    float h1 = s9 * (float)a01.y + 0.1f * h_hi(xq.x);
    float h2v = s9 * (float)a23.x + 0.1f * h_lo(xq.y);
    float h3 = s9 * (float)a23.y + 0.1f * h_hi(xq.y);
    float h4 = s9 * (float)a45.x + 0.1f * h_lo(xq.z);
    float h5 = s9 * (float)a45.y + 0.1f * h_hi(xq.z);
    float h6 = s9 * (float)a67.x + 0.1f * h_lo(xq.w);
    float h7 = s9 * (float)a67.y + 0.1f * h_hi(xq.w);
    if (mode == 0) {
        if (valid) {
            uint4 oq;
            oq.x = pack2h(gsc * h0, gsc * h1);
            oq.y = pack2h(gsc * h2v, gsc * h3);
            oq.z = pack2h(gsc * h4, gsc * h5);
            oq.w = pack2h(gsc * h6, gsc * h7);
            *(uint4*)(out + ((size_t)s * NNP + wid) * SF + fb8) = oq;
        }
    } else {
        h0 = fmaxf(h0, 0.f); h1 = fmaxf(h1, 0.f);
        h2v = fmaxf(h2v, 0.f); h3 = fmaxf(h3, 0.f);
        h4 = fmaxf(h4, 0.f); h5 = fmaxf(h5, 0.f);
        h6 = fmaxf(h6, 0.f); h7 = fmaxf(h7, 0.f);
        if (mode == 1) {
            if (valid) {
                u32x4 oq;
                oq.x = pack2bf(h0, h1);
                oq.y = pack2bf(h2v, h3);
                oq.z = pack2bf(h4, h5);
                oq.w = pack2bf(h6, h7);
                __builtin_nontemporal_store(
                    oq, (u32x4*)(out + (size_t)wid * NF + s * SF + fb8));
            }
        } else {
            int fb = s * SF + fb8;
            float4 wu0a = *(const float4*)(W3 + fb);
            float4 wu0b = *(const float4*)(W3 + fb + 4);
            float4 wv0a = *(const float4*)(W3 + 128 + fb);
            float4 wv0b = *(const float4*)(W3 + 128 + fb + 4);
            float4 wu1a = *(const float4*)(W3 + 256 + fb);
            float4 wu1b = *(const float4*)(W3 + 256 + fb + 4);
            float4 wv1a = *(const float4*)(W3 + 384 + fb);
            float4 wv1b = *(const float4*)(W3 + 384 + fb + 4);
            float du0 = h0 * wu0a.x + h1 * wu0a.y + h2v * wu0a.z + h3 * wu0a.w
                      + h4 * wu0b.x + h5 * wu0b.y + h6 * wu0b.z + h7 * wu0b.w;
            float du1 = h0 * wu1a.x + h1 * wu1a.y + h2v * wu1a.z + h3 * wu1a.w
                      + h4 * wu1b.x + h5 * wu1b.y + h6 * wu1b.z + h7 * wu1b.w;
            float dv0 = h0 * wv0a.x + h1 * wv0a.y + h2v * wv0a.z + h3 * wv0a.w
                      + h4 * wv0b.x + h5 * wv0b.y + h6 * wv0b.z + h7 * wv0b.w;
            float dv1 = h0 * wv1a.x + h1 * wv1a.y + h2v * wv1a.z + h3 * wv1a.w
                      + h4 * wv1b.x + h5 * wv1b.y + h6 * wv1b.z + h7 * wv1b.w;
            du0 += __shfl_xor(du0, 1, 64); du0 += __shfl_xor(du0, 2, 64);
            du0 += __shfl_xor(du0, 4, 64);
            du1 += __shfl_xor(du1, 1, 64); du1 += __shfl_xor(du1, 2, 64);
            du1 += __shfl_xor(du1, 4, 64);
            dv0 += __shfl_xor(dv0, 1, 64); dv0 += __shfl_xor(dv0, 2, 64);
            dv0 += __shfl_xor(dv0, 4, 64);
            dv1 += __shfl_xor(dv1, 1, 64); dv1 += __shfl_xor(dv1, 2, 64);
            dv1 += __shfl_xor(dv1, 4, 64);
            if (valid && fo < 4) {
                float v = (fo == 0) ? du0 : (fo == 1) ? du1
                          : (fo == 2) ? dv0 : dv1;
                atomicAdd(&puv[(size_t)wid * 4 + fo], v);
            }
        }
    }
}

// ---------------------------------------------------------------------------
// Pair head from precomputed projections: one thread per pair.
// ---------------------------------------------------------------------------
__global__ __launch_bounds__(256) void pair2_k(const float4* __restrict__ puv,
                                               const int2* __restrict__ index,
                                               const float* __restrict__ b3,
                                               float* __restrict__ outp) {
    int p = blockIdx.x * 256 + threadIdx.x;
    if (p >= NP) return;
    int2 uv = index[p];
    float4 a = puv[uv.x];
    float4 b = puv[uv.y];
    float s0 = a.x + b.z + b3[0];
    float s1 = a.y + b.w + b3[1];
    float m = fmaxf(s0, s1);
    float lse = m + logf(expf(s0 - m) + expf(s1 - m));
    *(float2*)(outp + (size_t)p * 2) = make_float2(s0 - lse, s1 - lse);
}

// ---------------------------------------------------------------------------
// Launch
// ---------------------------------------------------------------------------
extern "C" void kernel_launch(void* const* d_in, const int* in_sizes, int n_in,
                              void* d_out, int out_size, void* d_ws, size_t ws_size,
                              hipStream_t stream) {
    const float* x  = (const float*)d_in[0];
    const int* ei   = (const int*)d_in[1];
    const int* idx  = (const int*)d_in[2];
    const float* W1 = (const float*)d_in[3];
    const float* b1 = (const float*)d_in[4];
    const float* W2 = (const float*)d_in[5];
    const float* b2 = (const float*)d_in[6];
    const float* W3 = (const float*)d_in[7];
    const float* b3 = (const float*)d_in[8];
    float* out = (float*)d_out;

    char* ws = (char*)d_ws;
    size_t off = 0;
    auto alloc = [&](size_t bytes) -> void* {
        void* p = ws + off;
        off = (off + bytes + 255) & ~(size_t)255;
        return p;
    };
    const size_t HROWS = (size_t)NSL * NNP * SF;  // slice-major f16 state elems
    int*   cnt     = (int*)  alloc(NN * sizeof(int));
    float* dinv    = (float*)alloc(NN * sizeof(float));
    int*   row_ptr = (int*)  alloc((NN + 1) * sizeof(int));
    int*   bsum    = (int*)  alloc(NBLK * sizeof(int));
    int*   boff    = (int*)  alloc(NBLK * sizeof(int));
    int*   gtail   = (int*)  alloc(NBK * sizeof(int));
    int2*  gbk     = (int2*) alloc((size_t)NBK * BKCAP * sizeof(int2));  // 8 MB
    unsigned short* cols = (unsigned short*)alloc((size_t)NCPAD * 2);
    float4* puv    = (float4*)alloc((size_t)NN * sizeof(float4));
    unsigned short* Wb1 = (unsigned short*)alloc(128 * 128 * 2);
    unsigned short* Wb2 = (unsigned short*)alloc(128 * 128 * 2);
    unsigned short* Yu1 = (unsigned short*)alloc(HROWS * 2);
    unsigned short* Ys1 = (unsigned short*)alloc(HROWS * 2);
    unsigned short* Yu2 = (unsigned short*)alloc(HROWS * 2);
    unsigned short* Ys2 = (unsigned short*)alloc(HROWS * 2);
    unsigned short* HA  = (unsigned short*)alloc(HROWS * 2);
    unsigned short* HB  = (unsigned short*)alloc(HROWS * 2);
    unsigned short* Hrelu = (unsigned short*)alloc((size_t)NN * NF * 2);

    const int gN    = (NN + 255) / 256;
    const int gE    = (NE + 255) / 256;
    const int gBin  = (NE + EPB - 1) / EPB;
    const int gGemm = (NN + 63) / 64;             // wave per 16 rows
    const int gFill = (NCPAD / 2 + 255) / 256;
    const int gSlice = ((NN + 63) / 64) * 2;      // 1564 blocks, 512 thr
    const int gPair = (NP + 255) / 256;           // thread per pair

    // ---- weights + gcn_norm + padded binned CSR ----
    cast_w_k<<<8, 256, 0, stream>>>(W1, Wb1);
    cast_w_k<<<8, 256, 0, stream>>>(W2, Wb2);
    zero_k<<<1, 256, 0, stream>>>(Ys1, Ys2, HA, HB, gtail);
    init_cnt_k<<<gN, 256, 0, stream>>>(cnt, puv);
    count_k<<<gE, 256, 0, stream>>>(ei, cnt);
    scan_reduce_k<<<NBLK, 256, 0, stream>>>(cnt, bsum, dinv);
    scan_bsums_k<<<1, 256, 0, stream>>>(bsum, boff);
    scan_down_k<<<NBLK, 256, 0, stream>>>(cnt, boff, row_ptr);
    fill_cols_k<<<gFill, 256, 0, stream>>>((unsigned*)cols);
    bin_k<<<gBin, 256, 0, stream>>>(ei, gtail, gbk);
    build_k<<<NBK, 256, 0, stream>>>(row_ptr, gtail, gbk, cols);

    float* puvf = (float*)puv;
    // ---- layer 1 ----
    gemm_mfma_k<true><<<gGemm, 256, 0, stream>>>(x, Wb1, b1, dinv, Yu1, Ys1, NN);
    {
        const unsigned short* cur = Ys1;
        for (int k = 0; k < 10; ++k) {
            unsigned short* dst = (k == 9) ? Hrelu : ((k & 1) ? HB : HA);
            appnp_slice_k<<<gSlice, 512, 0, stream>>>(cur, Yu1, dinv, dst, row_ptr,
                                                      cols, (k == 9) ? 1 : 0, W3, puvf);
            cur = dst;
        }
    }
    // ---- layer 2 ----
    gemm_mfma_k<false><<<gGemm, 256, 0, stream>>>(Hrelu, Wb2, b2, dinv, Yu2, Ys2, NN);
    {
        const unsigned short* cur = Ys2;
        for (int k = 0; k < 10; ++k) {
            unsigned short* dst = (k & 1) ? HB : HA;
            appnp_slice_k<<<gSlice, 512, 0, stream>>>(cur, Yu2, dinv, dst, row_ptr,
                                                      cols, (k == 9) ? 2 : 0, W3, puvf);
            cur = dst;
        }
    }
    // ---- pair head ----
    pair2_k<<<gPair, 256, 0, stream>>>(puv, (const int2*)idx, b3, out);
}